// Round 6
// baseline (1184.914 us; speedup 1.0000x reference)
//
#include <hip/hip_runtime.h>
#include <math.h>

#define BB 16
#define CC 64
#define HS 128
#define HP 130
#define HPP 132
#define SLAB (CC * HPP)
#define KF 66
#define MM 12
#define EE 15
#define RR 4

__device__ __forceinline__ float gelu_f(float v) {
    return 0.5f * v * (1.0f + erff(v * 0.70710678118654752f));
}

// ---- table builder (runs once) ----
__global__ void k_tables(float* __restrict__ tw, float* __restrict__ Ct,
        float* __restrict__ Sn, float* __restrict__ Tb, float* __restrict__ TE) {
    int tid = blockIdx.x * blockDim.x + threadIdx.x;
    int nt = gridDim.x * blockDim.x;
    const double TP = 6.283185307179586476925286766559 / 130.0;
    for (int j = tid; j < HP; j += nt) {
        double a = TP * (double)j;
        tw[2 * j] = (float)cos(a); tw[2 * j + 1] = (float)sin(a);
    }
    for (int i = tid; i < 68 * 68; i += nt) {
        int w = i / 68, k = i % 68;
        Ct[i] = (float)cos(TP * (double)(w * k % HP));
    }
    for (int i = tid; i < 64 * 68; i += nt) {
        int j = i / 68, k = i % 68;
        Sn[i] = (float)(-sin(TP * (double)((j + 1) * k % HP)));
    }
    for (int i = tid; i < 64 * 68; i += nt) {
        int h = i / 68 + 1, l = i % 68;
        if (l < 66) {
            double a = TP * (double)(h * l % HP);
            Tb[2 * i] = (float)cos(a); Tb[2 * i + 1] = (float)sin(a);
        } else {
            Tb[2 * i] = 0.f; Tb[2 * i + 1] = 0.f;
        }
    }
    for (int i = tid; i < 24 * 132; i += nt) {
        int r = i / 132, w = i % 132;
        int t = r >> 1;
        double a = TP * (double)((w * t) % HP);
        TE[i] = (r & 1) ? (float)sin(a) : (float)cos(a);
    }
}

// ---- fc0: h layout [b][hh][c][w], pitch HPP ----
__global__ __launch_bounds__(256) void k_fc0(const float* __restrict__ x,
        const float* __restrict__ grd, const float* __restrict__ w,
        const float* __restrict__ bias, float* __restrict__ hdst) {
    int blk = blockIdx.x;
    int y = blk % HP, b = blk / HP;
    __shared__ float sin_[HS * 12];
    __shared__ float sw[12 * CC];
    __shared__ float sb[CC];
    int tid = threadIdx.x;
    for (int i = tid; i < 12 * CC; i += 256) sw[i] = w[i];
    if (tid < CC) sb[tid] = bias[tid];
    if (y < HS) {
        for (int i = tid; i < HS * 10; i += 256) {
            int xx = i / 10, t = i % 10;
            sin_[xx * 12 + t] = x[(((size_t)b * HS + y) * HS + xx) * 10 + t];
        }
        for (int i = tid; i < HS * 2; i += 256) {
            int xx = i / 2, t = i % 2;
            sin_[xx * 12 + 10 + t] = grd[(((size_t)b * HS + y) * HS + xx) * 2 + t];
        }
    }
    __syncthreads();
    for (int idx = tid; idx < CC * HP; idx += 256) {
        int c = idx / HP, xx = idx % HP;
        float v = 0.f;
        if (y < HS && xx < HS) {
            v = sb[c];
            #pragma unroll
            for (int t = 0; t < 12; ++t) v = fmaf(sin_[xx * 12 + t], sw[t * CC + c], v);
        }
        hdst[((size_t)(b * HP + y) * CC + c) * HPP + xx] = v;
    }
}

// ---- stage A v3c: row-split, 192 thr, LDS 17.4KB; manual 1-deep table prefetch
//      (R4: full unroll spilled to 256 VGPR; R5: unroll-1 serialized loads,
//       VALU 31%. Manual buf/cur double-buffer = k_conv's proven pattern.) ----
#define SDW2 132
__global__ __launch_bounds__(192, 3) void k_dftA(const float* __restrict__ hsrc,
        const float* __restrict__ Ct, const float* __restrict__ Sn,
        float* __restrict__ f1t) {
    int blk = blockIdx.x;
    int rq = blk & 3, bc = blk >> 2;
    int b = bc >> 6, c = bc & 63;
    int r0 = (rq >> 1) * 65 + (rq & 1) * 33;      // 0, 33, 65, 98
    int nw = (rq & 1) ? 32 : 33;                  // writable rows in this group
    int nst = (rq == 3) ? 32 : 33;                // stageable rows (row 130 doesn't exist)
    __shared__ __align__(16) float sd[33 * SDW2];
    int tid = threadIdx.x;
    const float* hp = hsrc + ((size_t)(b * HP + r0) * CC + c) * HPP;
    for (int i = tid; i < nst * HP; i += 192) {
        int r = i / HP, w = i % HP;
        sd[r * SDW2 + w] = hp[(size_t)r * SLAB + w];
    }
    if (rq == 3) {
        for (int i = tid; i < SDW2; i += 192) sd[32 * SDW2 + i] = 0.f;
    }
    __syncthreads();
    // s/d split: 33*64 = 2112 elems = 11 * 192 exactly
    float av[11], bv[11];
    #pragma unroll
    for (int q = 0; q < 11; ++q) {
        int i = tid + q * 192;
        int r = i >> 6, w = (i & 63) + 1;
        av[q] = sd[r * SDW2 + w];
        bv[q] = sd[r * SDW2 + (130 - w)];
    }
    __syncthreads();
    #pragma unroll
    for (int q = 0; q < 11; ++q) {
        int i = tid + q * 192;
        int r = i >> 6, w = (i & 63) + 1;
        sd[r * SDW2 + w] = av[q] + bv[q];
        sd[r * SDW2 + 67 + w] = av[q] - bv[q];
    }
    for (int i = tid; i < 33 * 2; i += 192) {
        int r = i >> 1; sd[r * SDW2 + 66 + (i & 1)] = 0.f;
    }
    __syncthreads();
    // 187 tasks = 11 rt (3 rows) x 17 kt (4 k)
    if (tid < 187) {
        int rt = tid / 17, kt = tid % 17;
        int rb = rt * 3, kb = kt * 4;
        float acc_re[3][4], acc_im[3][4];
        #pragma unroll
        for (int rr = 0; rr < 3; ++rr)
            #pragma unroll
            for (int kk = 0; kk < 4; ++kk) { acc_re[rr][kk] = 0.f; acc_im[rr][kk] = 0.f; }
        float4 buf[4];
        #pragma unroll
        for (int ww = 0; ww < 4; ++ww) buf[ww] = *(const float4*)&Ct[ww * 68 + kb];
        #pragma unroll 1
        for (int w0 = 0; w0 < 68; w0 += 4) {
            float4 cv[4] = {buf[0], buf[1], buf[2], buf[3]};
            int wn = (w0 + 4 < 68) ? (w0 + 4) : 0;   // last iter: dummy reload of row 0 (L1-hot)
            #pragma unroll
            for (int ww = 0; ww < 4; ++ww) buf[ww] = *(const float4*)&Ct[(wn + ww) * 68 + kb];
            #pragma unroll
            for (int rr = 0; rr < 3; ++rr) {
                float4 s4 = *(const float4*)&sd[(rb + rr) * SDW2 + w0];
                float svv[4] = {s4.x, s4.y, s4.z, s4.w};
                #pragma unroll
                for (int ww = 0; ww < 4; ++ww) {
                    acc_re[rr][0] = fmaf(svv[ww], cv[ww].x, acc_re[rr][0]);
                    acc_re[rr][1] = fmaf(svv[ww], cv[ww].y, acc_re[rr][1]);
                    acc_re[rr][2] = fmaf(svv[ww], cv[ww].z, acc_re[rr][2]);
                    acc_re[rr][3] = fmaf(svv[ww], cv[ww].w, acc_re[rr][3]);
                }
            }
        }
        #pragma unroll
        for (int ww = 0; ww < 4; ++ww) buf[ww] = *(const float4*)&Sn[ww * 68 + kb];
        #pragma unroll 1
        for (int j0 = 0; j0 < 64; j0 += 4) {
            float4 cv[4] = {buf[0], buf[1], buf[2], buf[3]};
            int jn = (j0 + 4 < 64) ? (j0 + 4) : 0;
            #pragma unroll
            for (int ww = 0; ww < 4; ++ww) buf[ww] = *(const float4*)&Sn[(jn + ww) * 68 + kb];
            #pragma unroll
            for (int rr = 0; rr < 3; ++rr) {
                float4 d4 = *(const float4*)&sd[(rb + rr) * SDW2 + 68 + j0];
                float dvv[4] = {d4.x, d4.y, d4.z, d4.w};
                #pragma unroll
                for (int ww = 0; ww < 4; ++ww) {
                    acc_im[rr][0] = fmaf(dvv[ww], cv[ww].x, acc_im[rr][0]);
                    acc_im[rr][1] = fmaf(dvv[ww], cv[ww].y, acc_im[rr][1]);
                    acc_im[rr][2] = fmaf(dvv[ww], cv[ww].z, acc_im[rr][2]);
                    acc_im[rr][3] = fmaf(dvv[ww], cv[ww].w, acc_im[rr][3]);
                }
            }
        }
        float2* outp = (float2*)f1t + (size_t)bc * HP * KF;
        #pragma unroll
        for (int rr = 0; rr < 3; ++rr) {
            int r = rb + rr;
            if (r < nw) {
                int hg = r0 + r;
                #pragma unroll
                for (int kk = 0; kk < 4; ++kk) {
                    int k = kb + kk;
                    if (k < KF)
                        outp[(size_t)hg * KF + k] = make_float2(acc_re[rr][kk], acc_im[rr][kk]);
                }
            }
        }
    }
}

// ---- stage B: column DFT; [4l][2k] 187 tasks + manual Tb prefetch ----
#define DBT 192
__global__ __launch_bounds__(DBT) void k_dftB(const float* __restrict__ f1t,
        const float* __restrict__ Tb, float* __restrict__ sumabs3,
        float* __restrict__ top, float* __restrict__ bot) {
    int blk = blockIdx.x;
    int kt3 = blk % 3, bc = blk / 3;
    int k0 = kt3 * 22;
    __shared__ __align__(16) float4 SD[64 * 24];
    __shared__ __align__(16) float2 sing[2 * 22];
    __shared__ float red[DBT];
    int tid = threadIdx.x;
    const float2* src = (const float2*)f1t + (size_t)bc * HP * KF + k0;
    for (int i = tid; i < 64 * 22; i += DBT) {
        int kk = i % 22, t = i / 22;
        int par = t >> 5, p = t & 31;
        int h = par ? (2 * p + 1) : (2 * p + 2);
        float2 a = src[(size_t)h * KF + kk], b = src[(size_t)(130 - h) * KF + kk];
        SD[t * 24 + kk] = make_float4(a.x + b.x, a.y + b.y, a.x - b.x, a.y - b.y);
    }
    if (tid < 128) {
        int t = tid >> 1, kk = 22 + (tid & 1);
        SD[t * 24 + kk] = make_float4(0.f, 0.f, 0.f, 0.f);
    }
    if (tid < 44) {
        int par = tid / 22, kk = tid % 22;
        sing[par * 22 + kk] = src[(size_t)(par ? 65 : 0) * KF + kk];
    }
    __syncthreads();
    float lsum = 0.f;
    int task = tid;
    if (task < 187) {
        int lt = task / 11, kt = task % 11;
        int l0 = 4 * lt, kb = 2 * kt;
        float aer[4][2], aei[4][2], aor[4][2], aoi[4][2];
        #pragma unroll
        for (int kk = 0; kk < 2; ++kk) {
            int k = kb + kk;
            float2 x0 = sing[k];
            float2 x6 = sing[22 + k];
            #pragma unroll
            for (int li = 0; li < 4; ++li) {
                float sg = (li & 1) ? -1.f : 1.f;
                aer[li][kk] = x0.x; aei[li][kk] = x0.y;
                aor[li][kk] = sg * x6.x; aoi[li][kk] = sg * x6.y;
            }
        }
        const float4* TbQ = (const float4*)Tb;
        float4 bA = TbQ[(68 + l0) >> 1];
        float4 bB = TbQ[((68 + l0) >> 1) + 1];
        float4 bC = TbQ[l0 >> 1];
        float4 bD = TbQ[(l0 >> 1) + 1];
        #pragma unroll 1
        for (int p = 0; p < 32; ++p) {
            float4 teA = bA, teB = bB, toA = bC, toB = bD;
            int pn = (p + 1 < 32) ? (p + 1) : 0;   // last iter: dummy reload (L1-hot)
            bA = TbQ[((2 * pn + 1) * 68 + l0) >> 1];
            bB = TbQ[(((2 * pn + 1) * 68 + l0) >> 1) + 1];
            bC = TbQ[((2 * pn) * 68 + l0) >> 1];
            bD = TbQ[(((2 * pn) * 68 + l0) >> 1) + 1];
            float tec[4] = {teA.x, teA.z, teB.x, teB.z};
            float tes[4] = {teA.y, teA.w, teB.y, teB.w};
            float toc[4] = {toA.x, toA.z, toB.x, toB.z};
            float tos[4] = {toA.y, toA.w, toB.y, toB.w};
            #pragma unroll
            for (int kk = 0; kk < 2; ++kk) {
                float4 e = SD[p * 24 + kb + kk];
                float4 o = SD[(32 + p) * 24 + kb + kk];
                #pragma unroll
                for (int li = 0; li < 4; ++li) {
                    aer[li][kk] = fmaf(e.x, tec[li], aer[li][kk]);
                    aer[li][kk] = fmaf(e.w, tes[li], aer[li][kk]);
                    aei[li][kk] = fmaf(e.y, tec[li], aei[li][kk]);
                    aei[li][kk] = fmaf(-e.z, tes[li], aei[li][kk]);
                    aor[li][kk] = fmaf(o.x, toc[li], aor[li][kk]);
                    aor[li][kk] = fmaf(o.w, tos[li], aor[li][kk]);
                    aoi[li][kk] = fmaf(o.y, toc[li], aoi[li][kk]);
                    aoi[li][kk] = fmaf(-o.z, tos[li], aoi[li][kk]);
                }
            }
        }
        float2* topp = (float2*)top + (size_t)bc * MM * MM;
        float2* botp = (float2*)bot + (size_t)bc * MM * MM;
        #pragma unroll
        for (int li = 0; li < 4; ++li) {
            int l = l0 + li;
            if (l < 65) {
                #pragma unroll
                for (int kk = 0; kk < 2; ++kk) {
                    int k = kb + kk;
                    float fr = aer[li][kk] + aor[li][kk];
                    float fi = aei[li][kk] + aoi[li][kk];
                    float gr = aer[li][kk] - aor[li][kk];
                    float gi = aei[li][kk] - aoi[li][kk];
                    lsum += sqrtf(fmaf(fr, fr, fi * fi)) + sqrtf(fmaf(gr, gr, gi * gi));
                    int kg = k0 + k;
                    if (kg < MM) {
                        if (l < MM) topp[l * MM + kg] = make_float2(fr, fi);
                        if (l >= 53) botp[(l - 53) * MM + kg] = make_float2(gr, gi);
                    }
                }
            }
        }
    }
    red[tid] = lsum;
    __syncthreads();
    if (tid < 64) red[tid] += red[tid + 64] + red[tid + 128];
    __syncthreads();
    for (int s = 32; s > 0; s >>= 1) {
        if (tid < s) red[tid] += red[tid + s];
        __syncthreads();
    }
    if (tid == 0) sumabs3[(size_t)bc * 3 + kt3] = red[0];
}

// ---- d1/d2 with gating fused; reads 3-way partial sums ----
__global__ __launch_bounds__(128) void k_moe(const float* __restrict__ sumabs3,
        const float* __restrict__ gw, const float* __restrict__ gb,
        const float* __restrict__ A1, const float* __restrict__ B1,
        const float* __restrict__ A2, const float* __restrict__ B2,
        float* __restrict__ d1, float* __restrict__ d2) {
    int blk = blockIdx.x;
    int i = blk % CC, b = blk / CC;
    __shared__ float ma[CC];
    __shared__ float lg[EE];
    __shared__ float gsh[EE];
    __shared__ float gA[2][EE * RR * 2];
    int tid = threadIdx.x;
    if (tid < CC) {
        const float* s3 = sumabs3 + (size_t)(b * CC + tid) * 3;
        ma[tid] = (s3[0] + s3[1] + s3[2]) * (1.0f / (float)(HP * KF));
    }
    __syncthreads();
    if (tid < EE) {
        float acc = gb[tid];
        for (int c = 0; c < CC; ++c) acc = fmaf(ma[c], gw[c * EE + tid], acc);
        lg[tid] = acc;
    }
    __syncthreads();
    if (tid == 0) {
        float mx = lg[0];
        for (int e = 1; e < EE; ++e) mx = fmaxf(mx, lg[e]);
        float s = 0.f, ex[EE];
        for (int e = 0; e < EE; ++e) { ex[e] = expf(lg[e] - mx); s += ex[e]; }
        float inv = 1.0f / s;
        for (int e = 0; e < EE; ++e) gsh[e] = ex[e] * inv;
    }
    __syncthreads();
    if (tid < 2 * EE * RR) {
        int which = tid / (EE * RR);
        int er = tid % (EE * RR);
        int e = er / RR, r = er % RR;
        const float* A = which ? A2 : A1;
        float gv = gsh[e];
        const float* ap = A + ((size_t)(e * CC + i) * RR + r) * 2;
        gA[which][er * 2]     = gv * ap[0];
        gA[which][er * 2 + 1] = gv * ap[1];
    }
    __syncthreads();
    int which = tid / CC, o = tid % CC;
    const float* Bm = which ? B2 : B1;
    float re = 0.f, im = 0.f;
    for (int er = 0; er < EE * RR; ++er) {
        int e = er / RR, r = er % RR;
        float ar = gA[which][er * 2], ai = gA[which][er * 2 + 1];
        const float* bp = Bm + ((size_t)(e * RR + r) * CC + o) * 2;
        float br = bp[0], bi = bp[1];
        re = fmaf(ar, br, re); re = fmaf(-ai, bi, re);
        im = fmaf(ar, bi, im); im = fmaf(ai, br, im);
    }
    float* dst = which ? d2 : d1;
    dst[((size_t)(b * CC + i) * CC + o) * 2]     = 0.1f * re;
    dst[((size_t)(b * CC + i) * CC + o) * 2 + 1] = 0.1f * im;
}

// ---- spectral multiply v2: b-quad register blocking, W read once per 4 batches ----
__global__ __launch_bounds__(192) void k_spec(
        const float* __restrict__ top, const float* __restrict__ W1_,
        const float* __restrict__ d1, float* __restrict__ otop,
        const float* __restrict__ bot, const float* __restrict__ W2_,
        const float* __restrict__ d2, float* __restrict__ obot) {
    int which = blockIdx.y;
    const float2* tp = (const float2*)(which ? bot : top);
    const float*  Wp = which ? W2_ : W1_;
    const float2* dp = (const float2*)(which ? d2 : d1);
    float2*       op = (float2*)(which ? obot : otop);
    int blk = blockIdx.x;                 // 256 blocks: o 0..63 x bq 0..3
    int o = blk & 63, b0 = (blk >> 6) * 4;
    int xy = threadIdx.x;
    if (xy >= MM * MM) return;
    const float2* wbase = (const float2*)Wp + (size_t)o * (MM * MM) + xy;
    const float2* tbase = tp + ((size_t)b0 * CC) * (MM * MM) + xy;
    const float2* dbase = dp + ((size_t)b0 * CC) * CC + o;
    float re[4] = {0.f, 0.f, 0.f, 0.f}, im[4] = {0.f, 0.f, 0.f, 0.f};
    #pragma unroll 2
    for (int i = 0; i < CC; ++i) {
        float2 wv = wbase[(size_t)i * (CC * MM * MM)];
        #pragma unroll
        for (int bb = 0; bb < 4; ++bb) {
            float2 tv = tbase[((size_t)bb * CC + i) * (MM * MM)];
            float2 dv = dbase[((size_t)bb * CC + i) * CC];
            float wr = wv.x + dv.x, wi = wv.y + dv.y;
            re[bb] = fmaf(tv.x, wr, re[bb]); re[bb] = fmaf(-tv.y, wi, re[bb]);
            im[bb] = fmaf(tv.x, wi, im[bb]); im[bb] = fmaf(tv.y, wr, im[bb]);
        }
    }
    #pragma unroll
    for (int bb = 0; bb < 4; ++bb)
        op[((size_t)(b0 + bb) * CC + o) * (MM * MM) + xy] = make_float2(re[bb], im[bb]);
}

// ---- inverse column ifft ----
__global__ __launch_bounds__(256) void k_icol(const float* __restrict__ otop,
        const float* __restrict__ obot, const float* __restrict__ tw,
        float* __restrict__ G) {
    int bc = blockIdx.x;
    __shared__ float otr[MM * MM], oti[MM * MM], obr[MM * MM], obi[MM * MM];
    __shared__ float c_[HP], s_[HP];
    int tid = threadIdx.x;
    for (int i = tid; i < HP; i += 256) {
        float2 t = ((const float2*)tw)[i];
        c_[i] = t.x; s_[i] = t.y;
    }
    const float2* tp = (const float2*)otop + (size_t)bc * MM * MM;
    const float2* bp = (const float2*)obot + (size_t)bc * MM * MM;
    if (tid < MM * MM) {
        float2 v = tp[tid]; otr[tid] = v.x; oti[tid] = v.y;
        float2 w = bp[tid]; obr[tid] = w.x; obi[tid] = w.y;
    }
    __syncthreads();
    float2* out = (float2*)G + (size_t)bc * HP * MM;
    const float inv = 1.0f / (float)HP;
    for (int idx = tid; idx < HP * MM; idx += 256) {
        int hh = idx / MM, k = idx % MM;
        float re = 0.f, im = 0.f;
        int j = 0;
        int j2 = (hh * (HP - MM)) % HP;
        for (int l = 0; l < MM; ++l) {
            float tc = c_[j], ts = s_[j];
            float ar = otr[l * MM + k], ai = oti[l * MM + k];
            re = fmaf(ar, tc, re); re = fmaf(-ai, ts, re);
            im = fmaf(ai, tc, im); im = fmaf(ar, ts, im);
            float tc2 = c_[j2], ts2 = s_[j2];
            float br = obr[l * MM + k], bi = obi[l * MM + k];
            re = fmaf(br, tc2, re); re = fmaf(-bi, ts2, re);
            im = fmaf(bi, tc2, im); im = fmaf(br, ts2, im);
            j += hh;  j  = (j  >= HP) ? j  - HP : j;
            j2 += hh; j2 = (j2 >= HP) ? j2 - HP : j2;
        }
        out[idx] = make_float2(re * inv, im * inv);
    }
}

// ---- fused conv + irfft GEMM v3: 256 thr, 256 tasks [8o][4w], 4 waves/block ----
#define CVT3 256
__global__ __launch_bounds__(CVT3) void k_conv(const float* __restrict__ hin,
        const float* __restrict__ G, const float* __restrict__ cw,
        const float* __restrict__ cb, const float* __restrict__ TE,
        float* __restrict__ hout, int do_gelu) {
    int lin = blockIdx.x;
    int tsk = (lin & 7) * 260 + (lin >> 3);
    int hh = tsk % HP, b = tsk / HP;
    __shared__ __align__(16) float As[88 * 68];
    __shared__ float cbl[CC];
    int tid = threadIdx.x;
    for (int i = tid; i < CC * CC; i += CVT3)
        As[(i % CC) * 68 + (i / CC)] = cw[i];
    const float2* gp = (const float2*)G;
    for (int i = tid; i < CC * MM; i += CVT3) {
        int o = i / MM, t = i % MM;
        float2 v = gp[(((size_t)b * CC + o) * HP + hh) * MM + t];
        float sc = ((t == 0) ? 1.0f : 2.0f) * (1.0f / (float)HP);
        As[(64 + 2 * t) * 68 + o] = sc * v.x;
        As[(65 + 2 * t) * 68 + o] = -sc * v.y;
    }
    if (tid < CC) cbl[tid] = cb[tid];
    __syncthreads();
    // ---- main: 256 tasks [8o][4w], covers w in [0,128) ----
    {
        int ot = tid >> 5, wt = tid & 31;
        int o0 = ot * 8, w0 = wt * 4;
        float acc[8][4];
        #pragma unroll
        for (int q = 0; q < 8; ++q) {
            float bq = cbl[o0 + q];
            acc[q][0] = bq; acc[q][1] = bq; acc[q][2] = bq; acc[q][3] = bq;
        }
        const float* hbase = hin + (size_t)(b * HP + hh) * SLAB + w0;
        float4 buf[4];
        #pragma unroll
        for (int j = 0; j < 4; ++j) buf[j] = *(const float4*)(hbase + j * HPP);
        #pragma unroll 1
        for (int ib = 0; ib < 16; ++ib) {
            float4 cur[4] = {buf[0], buf[1], buf[2], buf[3]};
            #pragma unroll
            for (int j = 0; j < 4; ++j)
                buf[j] = *(const float4*)(hbase + ((ib + 1) * 4 + j) * HPP);
            #pragma unroll
            for (int j = 0; j < 4; ++j) {
                int i = ib * 4 + j;
                float4 bv = cur[j];
                const float* ar = &As[i * 68 + o0];
                float4 a0 = *(const float4*)ar;
                float4 a1 = *(const float4*)(ar + 4);
                float aq[8] = {a0.x, a0.y, a0.z, a0.w, a1.x, a1.y, a1.z, a1.w};
                #pragma unroll
                for (int q = 0; q < 8; ++q) {
                    acc[q][0] = fmaf(aq[q], bv.x, acc[q][0]);
                    acc[q][1] = fmaf(aq[q], bv.y, acc[q][1]);
                    acc[q][2] = fmaf(aq[q], bv.z, acc[q][2]);
                    acc[q][3] = fmaf(aq[q], bv.w, acc[q][3]);
                }
            }
        }
        const float* tbase = TE + w0;
        #pragma unroll
        for (int j = 0; j < 4; ++j) buf[j] = *(const float4*)(tbase + j * 132);
        #pragma unroll 1
        for (int ib = 0; ib < 6; ++ib) {
            float4 cur[4] = {buf[0], buf[1], buf[2], buf[3]};
            #pragma unroll
            for (int j = 0; j < 4; ++j)
                buf[j] = *(const float4*)(tbase + ((ib + 1) * 4 + j) * 132);
            #pragma unroll
            for (int j = 0; j < 4; ++j) {
                int t = ib * 4 + j;
                float4 bv = cur[j];
                const float* ar = &As[(64 + t) * 68 + o0];
                float4 a0 = *(const float4*)ar;
                float4 a1 = *(const float4*)(ar + 4);
                float aq[8] = {a0.x, a0.y, a0.z, a0.w, a1.x, a1.y, a1.z, a1.w};
                #pragma unroll
                for (int q = 0; q < 8; ++q) {
                    acc[q][0] = fmaf(aq[q], bv.x, acc[q][0]);
                    acc[q][1] = fmaf(aq[q], bv.y, acc[q][1]);
                    acc[q][2] = fmaf(aq[q], bv.z, acc[q][2]);
                    acc[q][3] = fmaf(aq[q], bv.w, acc[q][3]);
                }
            }
        }
        #pragma unroll
        for (int q = 0; q < 8; ++q) {
            size_t orow = (size_t)(b * HP + hh) * SLAB + (size_t)(o0 + q) * HPP + w0;
            float4 ov;
            if (do_gelu) {
                ov.x = gelu_f(acc[q][0]); ov.y = gelu_f(acc[q][1]);
                ov.z = gelu_f(acc[q][2]); ov.w = gelu_f(acc[q][3]);
            } else {
                ov.x = acc[q][0]; ov.y = acc[q][1];
                ov.z = acc[q][2]; ov.w = acc[q][3];
            }
            *(float4*)&hout[orow] = ov;
        }
    }
    // ---- tail: w in {128,129}, one output per thread (cols 130/131 never read) ----
    if (tid < 128) {
        int o_t = tid >> 1, wsel = tid & 1;
        const float* hcol = hin + (size_t)(b * HP + hh) * SLAB + 128 + wsel;
        const float* tcol = TE + 128 + wsel;
        float accT = cbl[o_t];
        #pragma unroll 8
        for (int i = 0; i < CC; ++i)
            accT = fmaf(As[i * 68 + o_t], hcol[(size_t)i * HPP], accT);
        #pragma unroll 8
        for (int t = 0; t < 24; ++t)
            accT = fmaf(As[(64 + t) * 68 + o_t], tcol[t * 132], accT);
        if (do_gelu) accT = gelu_f(accT);
        hout[(size_t)(b * HP + hh) * SLAB + (size_t)o_t * HPP + 128 + wsel] = accT;
    }
}

// ---- head v3: 512 thr, wave-uniform j-tiles (scalar-pipe weights), hrT conflict-free ----
#define HDT 512
__global__ __launch_bounds__(HDT) void k_head(const float* __restrict__ hin,
        const float* __restrict__ fc1w, const float* __restrict__ fc1b,
        const float* __restrict__ fc2w, const float* __restrict__ fc2b,
        float* __restrict__ out) {
    int blk = blockIdx.x;
    int y = blk % HS, b = blk / HS;
    __shared__ float hrT[HS][CC + 1];   // [x][c], pitch 65 -> (lane+c)%32 banks, 2/bank
    __shared__ float part[8][HS];
    int tid = threadIdx.x;
    const float* hrow = hin + (size_t)(b * HP + y) * SLAB;
    for (int i = tid; i < CC * HS; i += HDT) {
        int c = i >> 7, w = i & 127;
        hrT[w][c] = hrow[(size_t)c * HPP + w];
    }
    __syncthreads();
    int lane = tid & 63;
    int wv = __builtin_amdgcn_readfirstlane(tid >> 6);   // 0..7, wave-uniform
    float accx = 0.f, accy = 0.f;
    #pragma unroll
    for (int pass = 0; pass < 2; ++pass) {
        int j0 = wv * 16 + pass * 8;
        const float* wbase = fc1w + j0;                  // wave-uniform base
        float t0[8], t1[8];
        #pragma unroll
        for (int q = 0; q < 8; ++q) { t0[q] = fc1b[j0 + q]; t1[q] = t0[q]; }
        for (int c = 0; c < CC; ++c) {
            float hx = hrT[lane][c];
            float hy = hrT[lane + 64][c];
            const float* wr = wbase + c * 128;           // wave-uniform -> s_load
            #pragma unroll
            for (int q = 0; q < 8; ++q) {
                float wq = wr[q];
                t0[q] = fmaf(hx, wq, t0[q]);
                t1[q] = fmaf(hy, wq, t1[q]);
            }
        }
        #pragma unroll
        for (int q = 0; q < 8; ++q) {
            float wj = fc2w[j0 + q];
            accx = fmaf(gelu_f(t0[q]), wj, accx);
            accy = fmaf(gelu_f(t1[q]), wj, accy);
        }
    }
    part[wv][lane] = accx;
    part[wv][lane + 64] = accy;
    __syncthreads();
    if (tid < HS) {
        float s = fc2b[0];
        #pragma unroll
        for (int g2 = 0; g2 < 8; ++g2) s += part[g2][tid];
        out[((size_t)b * HS + y) * HS + tid] = s;
    }
}

extern "C" void kernel_launch(void* const* d_in, const int* in_sizes, int n_in,
                              void* d_out, int out_size, void* d_ws, size_t ws_size,
                              hipStream_t stream) {
    (void)in_sizes; (void)n_in; (void)out_size; (void)ws_size;
    const float* x    = (const float*)d_in[0];
    const float* grd  = (const float*)d_in[1];
    const float* fc0w = (const float*)d_in[2];
    const float* fc0b = (const float*)d_in[3];
    const float* W1   = (const float*)d_in[4];
    const float* W2   = (const float*)d_in[5];
    const float* A1   = (const float*)d_in[6];
    const float* B1   = (const float*)d_in[7];
    const float* A2   = (const float*)d_in[8];
    const float* B2   = (const float*)d_in[9];
    const float* gw   = (const float*)d_in[10];
    const float* gb   = (const float*)d_in[11];
    const float* cw   = (const float*)d_in[12];
    const float* cb   = (const float*)d_in[13];
    const float* fc1w = (const float*)d_in[14];
    const float* fc1b = (const float*)d_in[15];
    const float* fc2w = (const float*)d_in[16];
    const float* fc2b = (const float*)d_in[17];
    float* out = (float*)d_out;

    float* ws = (float*)d_ws;
    size_t off = 0;
    auto alloc = [&](size_t n) {
        float* p = ws + off;
        off += (n + 63) & ~(size_t)63;
        return p;
    };
    float* tw      = alloc(2 * HP);
    float* Ct      = alloc(68 * 68);
    float* Sn      = alloc(64 * 68);
    float* Tb      = alloc(64 * 68 * 2);
    float* TE      = alloc(28 * 132);
    float* h_a     = alloc((size_t)BB * HP * SLAB + 8 * HPP);
    float* h_b     = alloc((size_t)BB * HP * SLAB + 8 * HPP);
    float* f1t     = alloc((size_t)BB * CC * HP * KF * 2);
    float* top     = alloc((size_t)BB * CC * MM * MM * 2);
    float* bot     = alloc((size_t)BB * CC * MM * MM * 2);
    float* otop    = alloc((size_t)BB * CC * MM * MM * 2);
    float* obot    = alloc((size_t)BB * CC * MM * MM * 2);
    float* sumabs3 = alloc(BB * CC * 3);
    float* d1      = alloc((size_t)BB * CC * CC * 2);
    float* d2      = alloc((size_t)BB * CC * CC * 2);

    hipLaunchKernelGGL(k_tables, dim3(40), dim3(256), 0, stream, tw, Ct, Sn, Tb, TE);
    hipLaunchKernelGGL(k_fc0, dim3(BB * HP), dim3(256), 0, stream, x, grd, fc0w, fc0b, h_a);

    float* hc = h_a;
    float* hn = h_b;
    for (int l = 0; l < 4; ++l) {
        hipLaunchKernelGGL(k_dftA, dim3(BB * CC * 4), dim3(192), 0, stream, hc, Ct, Sn, f1t);
        hipLaunchKernelGGL(k_dftB, dim3(BB * CC * 3), dim3(DBT), 0, stream,
                           f1t, Tb, sumabs3, top, bot);
        hipLaunchKernelGGL(k_moe, dim3(BB * CC), dim3(128), 0, stream, sumabs3,
                           gw + (size_t)l * CC * EE, gb + (size_t)l * EE,
                           A1 + (size_t)l * EE * CC * RR * 2, B1 + (size_t)l * EE * RR * CC * 2,
                           A2 + (size_t)l * EE * CC * RR * 2, B2 + (size_t)l * EE * RR * CC * 2,
                           d1, d2);
        hipLaunchKernelGGL(k_spec, dim3(256, 2), dim3(192), 0, stream,
                           top, W1 + (size_t)l * CC * CC * MM * MM * 2, d1, otop,
                           bot, W2 + (size_t)l * CC * CC * MM * MM * 2, d2, obot);
        hipLaunchKernelGGL(k_icol, dim3(BB * CC), dim3(256), 0, stream, otop, obot, tw, f1t);
        hipLaunchKernelGGL(k_conv, dim3(BB * HP), dim3(CVT3), 0, stream,
                           hc, f1t, cw + (size_t)l * CC * CC, cb + (size_t)l * CC, TE,
                           hn, (l < 3) ? 1 : 0);
        float* tswap = hc; hc = hn; hn = tswap;
    }
    hipLaunchKernelGGL(k_head, dim3(BB * HS), dim3(HDT), 0, stream,
                       hc, fc1w, fc1b, fc2w, fc2b, out);
}

// Round 7
// 1099.075 us; speedup vs baseline: 1.0781x; 1.0781x over previous
//
#include <hip/hip_runtime.h>
#include <math.h>

#define BB 16
#define CC 64
#define HS 128
#define HP 130
#define HPP 132
#define SLAB (CC * HPP)
#define KF 66
#define MM 12
#define EE 15
#define RR 4

__device__ __forceinline__ float gelu_f(float v) {
    return 0.5f * v * (1.0f + erff(v * 0.70710678118654752f));
}

// ---- table builder (runs once) ----
__global__ void k_tables(float* __restrict__ tw, float* __restrict__ Ct,
        float* __restrict__ Sn, float* __restrict__ Tb, float* __restrict__ TE) {
    int tid = blockIdx.x * blockDim.x + threadIdx.x;
    int nt = gridDim.x * blockDim.x;
    const double TP = 6.283185307179586476925286766559 / 130.0;
    for (int j = tid; j < HP; j += nt) {
        double a = TP * (double)j;
        tw[2 * j] = (float)cos(a); tw[2 * j + 1] = (float)sin(a);
    }
    for (int i = tid; i < 68 * 68; i += nt) {
        int w = i / 68, k = i % 68;
        Ct[i] = (float)cos(TP * (double)(w * k % HP));
    }
    for (int i = tid; i < 64 * 68; i += nt) {
        int j = i / 68, k = i % 68;
        Sn[i] = (float)(-sin(TP * (double)((j + 1) * k % HP)));
    }
    for (int i = tid; i < 64 * 68; i += nt) {
        int h = i / 68 + 1, l = i % 68;
        if (l < 66) {
            double a = TP * (double)(h * l % HP);
            Tb[2 * i] = (float)cos(a); Tb[2 * i + 1] = (float)sin(a);
        } else {
            Tb[2 * i] = 0.f; Tb[2 * i + 1] = 0.f;
        }
    }
    for (int i = tid; i < 24 * 132; i += nt) {
        int r = i / 132, w = i % 132;
        int t = r >> 1;
        double a = TP * (double)((w * t) % HP);
        TE[i] = (r & 1) ? (float)sin(a) : (float)cos(a);
    }
}

// ---- fc0: h layout [b][hh][c][w], pitch HPP ----
__global__ __launch_bounds__(256) void k_fc0(const float* __restrict__ x,
        const float* __restrict__ grd, const float* __restrict__ w,
        const float* __restrict__ bias, float* __restrict__ hdst) {
    int blk = blockIdx.x;
    int y = blk % HP, b = blk / HP;
    __shared__ float sin_[HS * 12];
    __shared__ float sw[12 * CC];
    __shared__ float sb[CC];
    int tid = threadIdx.x;
    for (int i = tid; i < 12 * CC; i += 256) sw[i] = w[i];
    if (tid < CC) sb[tid] = bias[tid];
    if (y < HS) {
        for (int i = tid; i < HS * 10; i += 256) {
            int xx = i / 10, t = i % 10;
            sin_[xx * 12 + t] = x[(((size_t)b * HS + y) * HS + xx) * 10 + t];
        }
        for (int i = tid; i < HS * 2; i += 256) {
            int xx = i / 2, t = i % 2;
            sin_[xx * 12 + 10 + t] = grd[(((size_t)b * HS + y) * HS + xx) * 2 + t];
        }
    }
    __syncthreads();
    for (int idx = tid; idx < CC * HP; idx += 256) {
        int c = idx / HP, xx = idx % HP;
        float v = 0.f;
        if (y < HS && xx < HS) {
            v = sb[c];
            #pragma unroll
            for (int t = 0; t < 12; ++t) v = fmaf(sin_[xx * 12 + t], sw[t * CC + c], v);
        }
        hdst[((size_t)(b * HP + y) * CC + c) * HPP + xx] = v;
    }
}

// ---- stage A (round-2 proven config): 256 thr, 65-row blocks, 5x4 tile, SDW 136.
//      Measured 73.2 us @ VALU 41%. R2-vs-R6 A/B: 5-row amortization (80 FMA/table
//      load) beats 3-row+prefetch+occupancy (88.2 us). Do not shrink the tile. ----
#define SDW 136
__global__ __launch_bounds__(256) void k_dftA(const float* __restrict__ hsrc,
        const float* __restrict__ Ct, const float* __restrict__ Sn,
        float* __restrict__ f1t) {
    int blk = blockIdx.x;
    int rh = blk & 1, bc = blk >> 1;
    int b = bc >> 6, c = bc & 63;
    int r0 = rh * 65;
    __shared__ __align__(16) float sd[70 * SDW];
    int tid = threadIdx.x;
    const float* hp = hsrc + ((size_t)(b * HP + r0) * CC + c) * HPP;
    for (int i = tid; i < 65 * HP; i += 256) {
        int r = i / HP, w = i % HP;
        sd[r * SDW + w] = hp[(size_t)r * SLAB + w];
    }
    for (int i = tid; i < 5 * SDW; i += 256) sd[65 * SDW + i] = 0.f;
    for (int i = tid; i < 65 * 6; i += 256) {
        int r = i / 6, cc2 = 130 + i % 6; sd[r * SDW + cc2] = 0.f;
    }
    __syncthreads();
    float av[17], bv[17];
    #pragma unroll
    for (int cq = 0; cq < 17; ++cq) {
        int i = tid + cq * 256;
        if (i < 65 * 64) {
            int r = i >> 6, w = (i & 63) + 1;
            av[cq] = sd[r * SDW + w];
            bv[cq] = sd[r * SDW + (130 - w)];
        }
    }
    __syncthreads();
    #pragma unroll
    for (int cq = 0; cq < 17; ++cq) {
        int i = tid + cq * 256;
        if (i < 65 * 64) {
            int r = i >> 6, w = (i & 63) + 1;
            sd[r * SDW + w] = av[cq] + bv[cq];
            sd[r * SDW + 67 + w] = av[cq] - bv[cq];
        }
    }
    for (int i = tid; i < 65 * 2; i += 256) {
        int r = i >> 1, cc2 = 66 + (i & 1); sd[r * SDW + cc2] = 0.f;
    }
    __syncthreads();
    int task = tid;
    if (task < 238) {
        int rt = task / 17, kt = task % 17;
        int rb = rt * 5, kb = kt * 4;
        float acc_re[5][4], acc_im[5][4];
        #pragma unroll
        for (int rr = 0; rr < 5; ++rr)
            #pragma unroll
            for (int kk = 0; kk < 4; ++kk) { acc_re[rr][kk] = 0.f; acc_im[rr][kk] = 0.f; }
        for (int w0 = 0; w0 < 68; w0 += 4) {
            float4 cv[4];
            #pragma unroll
            for (int ww = 0; ww < 4; ++ww) cv[ww] = *(const float4*)&Ct[(w0 + ww) * 68 + kb];
            #pragma unroll
            for (int rr = 0; rr < 5; ++rr) {
                float4 s4 = *(const float4*)&sd[(rb + rr) * SDW + w0];
                float svv[4] = {s4.x, s4.y, s4.z, s4.w};
                #pragma unroll
                for (int ww = 0; ww < 4; ++ww) {
                    acc_re[rr][0] = fmaf(svv[ww], cv[ww].x, acc_re[rr][0]);
                    acc_re[rr][1] = fmaf(svv[ww], cv[ww].y, acc_re[rr][1]);
                    acc_re[rr][2] = fmaf(svv[ww], cv[ww].z, acc_re[rr][2]);
                    acc_re[rr][3] = fmaf(svv[ww], cv[ww].w, acc_re[rr][3]);
                }
            }
        }
        for (int j0 = 0; j0 < 64; j0 += 4) {
            float4 cv[4];
            #pragma unroll
            for (int ww = 0; ww < 4; ++ww) cv[ww] = *(const float4*)&Sn[(j0 + ww) * 68 + kb];
            #pragma unroll
            for (int rr = 0; rr < 5; ++rr) {
                float4 d4 = *(const float4*)&sd[(rb + rr) * SDW + 68 + j0];
                float dvv[4] = {d4.x, d4.y, d4.z, d4.w};
                #pragma unroll
                for (int ww = 0; ww < 4; ++ww) {
                    acc_im[rr][0] = fmaf(dvv[ww], cv[ww].x, acc_im[rr][0]);
                    acc_im[rr][1] = fmaf(dvv[ww], cv[ww].y, acc_im[rr][1]);
                    acc_im[rr][2] = fmaf(dvv[ww], cv[ww].z, acc_im[rr][2]);
                    acc_im[rr][3] = fmaf(dvv[ww], cv[ww].w, acc_im[rr][3]);
                }
            }
        }
        float2* outp = (float2*)f1t + (size_t)bc * HP * KF;
        #pragma unroll
        for (int rr = 0; rr < 5; ++rr) {
            int r = rb + rr;
            if (r < 65) {
                int hg = r0 + r;
                #pragma unroll
                for (int kk = 0; kk < 4; ++kk) {
                    int k = kb + kk;
                    if (k < KF)
                        outp[(size_t)hg * KF + k] = make_float2(acc_re[rr][kk], acc_im[rr][kk]);
                }
            }
        }
    }
}

// ---- stage B (round-2/3 proven config): [4l][2k] 187 tasks, compiler-scheduled ----
#define DBT 192
__global__ __launch_bounds__(DBT) void k_dftB(const float* __restrict__ f1t,
        const float* __restrict__ Tb, float* __restrict__ sumabs3,
        float* __restrict__ top, float* __restrict__ bot) {
    int blk = blockIdx.x;
    int kt3 = blk % 3, bc = blk / 3;
    int k0 = kt3 * 22;
    __shared__ __align__(16) float4 SD[64 * 24];
    __shared__ __align__(16) float2 sing[2 * 22];
    __shared__ float red[DBT];
    int tid = threadIdx.x;
    const float2* src = (const float2*)f1t + (size_t)bc * HP * KF + k0;
    for (int i = tid; i < 64 * 22; i += DBT) {
        int kk = i % 22, t = i / 22;
        int par = t >> 5, p = t & 31;
        int h = par ? (2 * p + 1) : (2 * p + 2);
        float2 a = src[(size_t)h * KF + kk], b = src[(size_t)(130 - h) * KF + kk];
        SD[t * 24 + kk] = make_float4(a.x + b.x, a.y + b.y, a.x - b.x, a.y - b.y);
    }
    if (tid < 128) {
        int t = tid >> 1, kk = 22 + (tid & 1);
        SD[t * 24 + kk] = make_float4(0.f, 0.f, 0.f, 0.f);
    }
    if (tid < 44) {
        int par = tid / 22, kk = tid % 22;
        sing[par * 22 + kk] = src[(size_t)(par ? 65 : 0) * KF + kk];
    }
    __syncthreads();
    float lsum = 0.f;
    int task = tid;
    if (task < 187) {
        int lt = task / 11, kt = task % 11;
        int l0 = 4 * lt, kb = 2 * kt;
        float aer[4][2], aei[4][2], aor[4][2], aoi[4][2];
        #pragma unroll
        for (int kk = 0; kk < 2; ++kk) {
            int k = kb + kk;
            float2 x0 = sing[k];
            float2 x6 = sing[22 + k];
            #pragma unroll
            for (int li = 0; li < 4; ++li) {
                float sg = (li & 1) ? -1.f : 1.f;
                aer[li][kk] = x0.x; aei[li][kk] = x0.y;
                aor[li][kk] = sg * x6.x; aoi[li][kk] = sg * x6.y;
            }
        }
        const float4* TbQ = (const float4*)Tb;
        for (int p = 0; p < 32; ++p) {
            float4 teA = TbQ[((2 * p + 1) * 68 + l0) >> 1];
            float4 teB = TbQ[(((2 * p + 1) * 68 + l0) >> 1) + 1];
            float4 toA = TbQ[((2 * p) * 68 + l0) >> 1];
            float4 toB = TbQ[(((2 * p) * 68 + l0) >> 1) + 1];
            float tec[4] = {teA.x, teA.z, teB.x, teB.z};
            float tes[4] = {teA.y, teA.w, teB.y, teB.w};
            float toc[4] = {toA.x, toA.z, toB.x, toB.z};
            float tos[4] = {toA.y, toA.w, toB.y, toB.w};
            #pragma unroll
            for (int kk = 0; kk < 2; ++kk) {
                float4 e = SD[p * 24 + kb + kk];
                float4 o = SD[(32 + p) * 24 + kb + kk];
                #pragma unroll
                for (int li = 0; li < 4; ++li) {
                    aer[li][kk] = fmaf(e.x, tec[li], aer[li][kk]);
                    aer[li][kk] = fmaf(e.w, tes[li], aer[li][kk]);
                    aei[li][kk] = fmaf(e.y, tec[li], aei[li][kk]);
                    aei[li][kk] = fmaf(-e.z, tes[li], aei[li][kk]);
                    aor[li][kk] = fmaf(o.x, toc[li], aor[li][kk]);
                    aor[li][kk] = fmaf(o.w, tos[li], aor[li][kk]);
                    aoi[li][kk] = fmaf(o.y, toc[li], aoi[li][kk]);
                    aoi[li][kk] = fmaf(-o.z, tos[li], aoi[li][kk]);
                }
            }
        }
        float2* topp = (float2*)top + (size_t)bc * MM * MM;
        float2* botp = (float2*)bot + (size_t)bc * MM * MM;
        #pragma unroll
        for (int li = 0; li < 4; ++li) {
            int l = l0 + li;
            if (l < 65) {
                #pragma unroll
                for (int kk = 0; kk < 2; ++kk) {
                    int k = kb + kk;
                    float fr = aer[li][kk] + aor[li][kk];
                    float fi = aei[li][kk] + aoi[li][kk];
                    float gr = aer[li][kk] - aor[li][kk];
                    float gi = aei[li][kk] - aoi[li][kk];
                    lsum += sqrtf(fmaf(fr, fr, fi * fi)) + sqrtf(fmaf(gr, gr, gi * gi));
                    int kg = k0 + k;
                    if (kg < MM) {
                        if (l < MM) topp[l * MM + kg] = make_float2(fr, fi);
                        if (l >= 53) botp[(l - 53) * MM + kg] = make_float2(gr, gi);
                    }
                }
            }
        }
    }
    red[tid] = lsum;
    __syncthreads();
    if (tid < 64) red[tid] += red[tid + 64] + red[tid + 128];
    __syncthreads();
    for (int s = 32; s > 0; s >>= 1) {
        if (tid < s) red[tid] += red[tid + s];
        __syncthreads();
    }
    if (tid == 0) sumabs3[(size_t)bc * 3 + kt3] = red[0];
}

// ---- d1/d2 with gating fused; reads 3-way partial sums ----
__global__ __launch_bounds__(128) void k_moe(const float* __restrict__ sumabs3,
        const float* __restrict__ gw, const float* __restrict__ gb,
        const float* __restrict__ A1, const float* __restrict__ B1,
        const float* __restrict__ A2, const float* __restrict__ B2,
        float* __restrict__ d1, float* __restrict__ d2) {
    int blk = blockIdx.x;
    int i = blk % CC, b = blk / CC;
    __shared__ float ma[CC];
    __shared__ float lg[EE];
    __shared__ float gsh[EE];
    __shared__ float gA[2][EE * RR * 2];
    int tid = threadIdx.x;
    if (tid < CC) {
        const float* s3 = sumabs3 + (size_t)(b * CC + tid) * 3;
        ma[tid] = (s3[0] + s3[1] + s3[2]) * (1.0f / (float)(HP * KF));
    }
    __syncthreads();
    if (tid < EE) {
        float acc = gb[tid];
        for (int c = 0; c < CC; ++c) acc = fmaf(ma[c], gw[c * EE + tid], acc);
        lg[tid] = acc;
    }
    __syncthreads();
    if (tid == 0) {
        float mx = lg[0];
        for (int e = 1; e < EE; ++e) mx = fmaxf(mx, lg[e]);
        float s = 0.f, ex[EE];
        for (int e = 0; e < EE; ++e) { ex[e] = expf(lg[e] - mx); s += ex[e]; }
        float inv = 1.0f / s;
        for (int e = 0; e < EE; ++e) gsh[e] = ex[e] * inv;
    }
    __syncthreads();
    if (tid < 2 * EE * RR) {
        int which = tid / (EE * RR);
        int er = tid % (EE * RR);
        int e = er / RR, r = er % RR;
        const float* A = which ? A2 : A1;
        float gv = gsh[e];
        const float* ap = A + ((size_t)(e * CC + i) * RR + r) * 2;
        gA[which][er * 2]     = gv * ap[0];
        gA[which][er * 2 + 1] = gv * ap[1];
    }
    __syncthreads();
    int which = tid / CC, o = tid % CC;
    const float* Bm = which ? B2 : B1;
    float re = 0.f, im = 0.f;
    for (int er = 0; er < EE * RR; ++er) {
        int e = er / RR, r = er % RR;
        float ar = gA[which][er * 2], ai = gA[which][er * 2 + 1];
        const float* bp = Bm + ((size_t)(e * RR + r) * CC + o) * 2;
        float br = bp[0], bi = bp[1];
        re = fmaf(ar, br, re); re = fmaf(-ai, bi, re);
        im = fmaf(ar, bi, im); im = fmaf(ai, br, im);
    }
    float* dst = which ? d2 : d1;
    dst[((size_t)(b * CC + i) * CC + o) * 2]     = 0.1f * re;
    dst[((size_t)(b * CC + i) * CC + o) * 2 + 1] = 0.1f * im;
}

// ---- spectral multiply v2: b-quad register blocking, W read once per 4 batches ----
__global__ __launch_bounds__(192) void k_spec(
        const float* __restrict__ top, const float* __restrict__ W1_,
        const float* __restrict__ d1, float* __restrict__ otop,
        const float* __restrict__ bot, const float* __restrict__ W2_,
        const float* __restrict__ d2, float* __restrict__ obot) {
    int which = blockIdx.y;
    const float2* tp = (const float2*)(which ? bot : top);
    const float*  Wp = which ? W2_ : W1_;
    const float2* dp = (const float2*)(which ? d2 : d1);
    float2*       op = (float2*)(which ? obot : otop);
    int blk = blockIdx.x;                 // 256 blocks: o 0..63 x bq 0..3
    int o = blk & 63, b0 = (blk >> 6) * 4;
    int xy = threadIdx.x;
    if (xy >= MM * MM) return;
    const float2* wbase = (const float2*)Wp + (size_t)o * (MM * MM) + xy;
    const float2* tbase = tp + ((size_t)b0 * CC) * (MM * MM) + xy;
    const float2* dbase = dp + ((size_t)b0 * CC) * CC + o;
    float re[4] = {0.f, 0.f, 0.f, 0.f}, im[4] = {0.f, 0.f, 0.f, 0.f};
    #pragma unroll 2
    for (int i = 0; i < CC; ++i) {
        float2 wv = wbase[(size_t)i * (CC * MM * MM)];
        #pragma unroll
        for (int bb = 0; bb < 4; ++bb) {
            float2 tv = tbase[((size_t)bb * CC + i) * (MM * MM)];
            float2 dv = dbase[((size_t)bb * CC + i) * CC];
            float wr = wv.x + dv.x, wi = wv.y + dv.y;
            re[bb] = fmaf(tv.x, wr, re[bb]); re[bb] = fmaf(-tv.y, wi, re[bb]);
            im[bb] = fmaf(tv.x, wi, im[bb]); im[bb] = fmaf(tv.y, wr, im[bb]);
        }
    }
    #pragma unroll
    for (int bb = 0; bb < 4; ++bb)
        op[((size_t)(b0 + bb) * CC + o) * (MM * MM) + xy] = make_float2(re[bb], im[bb]);
}

// ---- inverse column ifft ----
__global__ __launch_bounds__(256) void k_icol(const float* __restrict__ otop,
        const float* __restrict__ obot, const float* __restrict__ tw,
        float* __restrict__ G) {
    int bc = blockIdx.x;
    __shared__ float otr[MM * MM], oti[MM * MM], obr[MM * MM], obi[MM * MM];
    __shared__ float c_[HP], s_[HP];
    int tid = threadIdx.x;
    for (int i = tid; i < HP; i += 256) {
        float2 t = ((const float2*)tw)[i];
        c_[i] = t.x; s_[i] = t.y;
    }
    const float2* tp = (const float2*)otop + (size_t)bc * MM * MM;
    const float2* bp = (const float2*)obot + (size_t)bc * MM * MM;
    if (tid < MM * MM) {
        float2 v = tp[tid]; otr[tid] = v.x; oti[tid] = v.y;
        float2 w = bp[tid]; obr[tid] = w.x; obi[tid] = w.y;
    }
    __syncthreads();
    float2* out = (float2*)G + (size_t)bc * HP * MM;
    const float inv = 1.0f / (float)HP;
    for (int idx = tid; idx < HP * MM; idx += 256) {
        int hh = idx / MM, k = idx % MM;
        float re = 0.f, im = 0.f;
        int j = 0;
        int j2 = (hh * (HP - MM)) % HP;
        for (int l = 0; l < MM; ++l) {
            float tc = c_[j], ts = s_[j];
            float ar = otr[l * MM + k], ai = oti[l * MM + k];
            re = fmaf(ar, tc, re); re = fmaf(-ai, ts, re);
            im = fmaf(ai, tc, im); im = fmaf(ar, ts, im);
            float tc2 = c_[j2], ts2 = s_[j2];
            float br = obr[l * MM + k], bi = obi[l * MM + k];
            re = fmaf(br, tc2, re); re = fmaf(-bi, ts2, re);
            im = fmaf(bi, tc2, im); im = fmaf(br, ts2, im);
            j += hh;  j  = (j  >= HP) ? j  - HP : j;
            j2 += hh; j2 = (j2 >= HP) ? j2 - HP : j2;
        }
        out[idx] = make_float2(re * inv, im * inv);
    }
}

// ---- fused conv + irfft GEMM v3: 256 thr, 256 tasks [8o][4w], 4 waves/block ----
#define CVT3 256
__global__ __launch_bounds__(CVT3) void k_conv(const float* __restrict__ hin,
        const float* __restrict__ G, const float* __restrict__ cw,
        const float* __restrict__ cb, const float* __restrict__ TE,
        float* __restrict__ hout, int do_gelu) {
    int lin = blockIdx.x;
    int tsk = (lin & 7) * 260 + (lin >> 3);
    int hh = tsk % HP, b = tsk / HP;
    __shared__ __align__(16) float As[88 * 68];
    __shared__ float cbl[CC];
    int tid = threadIdx.x;
    for (int i = tid; i < CC * CC; i += CVT3)
        As[(i % CC) * 68 + (i / CC)] = cw[i];
    const float2* gp = (const float2*)G;
    for (int i = tid; i < CC * MM; i += CVT3) {
        int o = i / MM, t = i % MM;
        float2 v = gp[(((size_t)b * CC + o) * HP + hh) * MM + t];
        float sc = ((t == 0) ? 1.0f : 2.0f) * (1.0f / (float)HP);
        As[(64 + 2 * t) * 68 + o] = sc * v.x;
        As[(65 + 2 * t) * 68 + o] = -sc * v.y;
    }
    if (tid < CC) cbl[tid] = cb[tid];
    __syncthreads();
    // ---- main: 256 tasks [8o][4w], covers w in [0,128) ----
    {
        int ot = tid >> 5, wt = tid & 31;
        int o0 = ot * 8, w0 = wt * 4;
        float acc[8][4];
        #pragma unroll
        for (int q = 0; q < 8; ++q) {
            float bq = cbl[o0 + q];
            acc[q][0] = bq; acc[q][1] = bq; acc[q][2] = bq; acc[q][3] = bq;
        }
        const float* hbase = hin + (size_t)(b * HP + hh) * SLAB + w0;
        float4 buf[4];
        #pragma unroll
        for (int j = 0; j < 4; ++j) buf[j] = *(const float4*)(hbase + j * HPP);
        #pragma unroll 1
        for (int ib = 0; ib < 16; ++ib) {
            float4 cur[4] = {buf[0], buf[1], buf[2], buf[3]};
            #pragma unroll
            for (int j = 0; j < 4; ++j)
                buf[j] = *(const float4*)(hbase + ((ib + 1) * 4 + j) * HPP);
            #pragma unroll
            for (int j = 0; j < 4; ++j) {
                int i = ib * 4 + j;
                float4 bv = cur[j];
                const float* ar = &As[i * 68 + o0];
                float4 a0 = *(const float4*)ar;
                float4 a1 = *(const float4*)(ar + 4);
                float aq[8] = {a0.x, a0.y, a0.z, a0.w, a1.x, a1.y, a1.z, a1.w};
                #pragma unroll
                for (int q = 0; q < 8; ++q) {
                    acc[q][0] = fmaf(aq[q], bv.x, acc[q][0]);
                    acc[q][1] = fmaf(aq[q], bv.y, acc[q][1]);
                    acc[q][2] = fmaf(aq[q], bv.z, acc[q][2]);
                    acc[q][3] = fmaf(aq[q], bv.w, acc[q][3]);
                }
            }
        }
        const float* tbase = TE + w0;
        #pragma unroll
        for (int j = 0; j < 4; ++j) buf[j] = *(const float4*)(tbase + j * 132);
        #pragma unroll 1
        for (int ib = 0; ib < 6; ++ib) {
            float4 cur[4] = {buf[0], buf[1], buf[2], buf[3]};
            #pragma unroll
            for (int j = 0; j < 4; ++j)
                buf[j] = *(const float4*)(tbase + ((ib + 1) * 4 + j) * 132);
            #pragma unroll
            for (int j = 0; j < 4; ++j) {
                int t = ib * 4 + j;
                float4 bv = cur[j];
                const float* ar = &As[(64 + t) * 68 + o0];
                float4 a0 = *(const float4*)ar;
                float4 a1 = *(const float4*)(ar + 4);
                float aq[8] = {a0.x, a0.y, a0.z, a0.w, a1.x, a1.y, a1.z, a1.w};
                #pragma unroll
                for (int q = 0; q < 8; ++q) {
                    acc[q][0] = fmaf(aq[q], bv.x, acc[q][0]);
                    acc[q][1] = fmaf(aq[q], bv.y, acc[q][1]);
                    acc[q][2] = fmaf(aq[q], bv.z, acc[q][2]);
                    acc[q][3] = fmaf(aq[q], bv.w, acc[q][3]);
                }
            }
        }
        #pragma unroll
        for (int q = 0; q < 8; ++q) {
            size_t orow = (size_t)(b * HP + hh) * SLAB + (size_t)(o0 + q) * HPP + w0;
            float4 ov;
            if (do_gelu) {
                ov.x = gelu_f(acc[q][0]); ov.y = gelu_f(acc[q][1]);
                ov.z = gelu_f(acc[q][2]); ov.w = gelu_f(acc[q][3]);
            } else {
                ov.x = acc[q][0]; ov.y = acc[q][1];
                ov.z = acc[q][2]; ov.w = acc[q][3];
            }
            *(float4*)&hout[orow] = ov;
        }
    }
    // ---- tail: w in {128,129}, one output per thread (cols 130/131 never read) ----
    if (tid < 128) {
        int o_t = tid >> 1, wsel = tid & 1;
        const float* hcol = hin + (size_t)(b * HP + hh) * SLAB + 128 + wsel;
        const float* tcol = TE + 128 + wsel;
        float accT = cbl[o_t];
        #pragma unroll 8
        for (int i = 0; i < CC; ++i)
            accT = fmaf(As[i * 68 + o_t], hcol[(size_t)i * HPP], accT);
        #pragma unroll 8
        for (int t = 0; t < 24; ++t)
            accT = fmaf(As[(64 + t) * 68 + o_t], tcol[t * 132], accT);
        if (do_gelu) accT = gelu_f(accT);
        hout[(size_t)(b * HP + hh) * SLAB + (size_t)o_t * HPP + 128 + wsel] = accT;
    }
}

// ---- head v3: 512 thr, wave-uniform j-tiles (scalar-pipe weights), hrT conflict-free ----
#define HDT 512
__global__ __launch_bounds__(HDT) void k_head(const float* __restrict__ hin,
        const float* __restrict__ fc1w, const float* __restrict__ fc1b,
        const float* __restrict__ fc2w, const float* __restrict__ fc2b,
        float* __restrict__ out) {
    int blk = blockIdx.x;
    int y = blk % HS, b = blk / HS;
    __shared__ float hrT[HS][CC + 1];   // [x][c], pitch 65 -> (lane+c)%32 banks, 2/bank
    __shared__ float part[8][HS];
    int tid = threadIdx.x;
    const float* hrow = hin + (size_t)(b * HP + y) * SLAB;
    for (int i = tid; i < CC * HS; i += HDT) {
        int c = i >> 7, w = i & 127;
        hrT[w][c] = hrow[(size_t)c * HPP + w];
    }
    __syncthreads();
    int lane = tid & 63;
    int wv = __builtin_amdgcn_readfirstlane(tid >> 6);   // 0..7, wave-uniform
    float accx = 0.f, accy = 0.f;
    #pragma unroll
    for (int pass = 0; pass < 2; ++pass) {
        int j0 = wv * 16 + pass * 8;
        const float* wbase = fc1w + j0;                  // wave-uniform base
        float t0[8], t1[8];
        #pragma unroll
        for (int q = 0; q < 8; ++q) { t0[q] = fc1b[j0 + q]; t1[q] = t0[q]; }
        for (int c = 0; c < CC; ++c) {
            float hx = hrT[lane][c];
            float hy = hrT[lane + 64][c];
            const float* wr = wbase + c * 128;           // wave-uniform -> s_load
            #pragma unroll
            for (int q = 0; q < 8; ++q) {
                float wq = wr[q];
                t0[q] = fmaf(hx, wq, t0[q]);
                t1[q] = fmaf(hy, wq, t1[q]);
            }
        }
        #pragma unroll
        for (int q = 0; q < 8; ++q) {
            float wj = fc2w[j0 + q];
            accx = fmaf(gelu_f(t0[q]), wj, accx);
            accy = fmaf(gelu_f(t1[q]), wj, accy);
        }
    }
    part[wv][lane] = accx;
    part[wv][lane + 64] = accy;
    __syncthreads();
    if (tid < HS) {
        float s = fc2b[0];
        #pragma unroll
        for (int g2 = 0; g2 < 8; ++g2) s += part[g2][tid];
        out[((size_t)b * HS + y) * HS + tid] = s;
    }
}

extern "C" void kernel_launch(void* const* d_in, const int* in_sizes, int n_in,
                              void* d_out, int out_size, void* d_ws, size_t ws_size,
                              hipStream_t stream) {
    (void)in_sizes; (void)n_in; (void)out_size; (void)ws_size;
    const float* x    = (const float*)d_in[0];
    const float* grd  = (const float*)d_in[1];
    const float* fc0w = (const float*)d_in[2];
    const float* fc0b = (const float*)d_in[3];
    const float* W1   = (const float*)d_in[4];
    const float* W2   = (const float*)d_in[5];
    const float* A1   = (const float*)d_in[6];
    const float* B1   = (const float*)d_in[7];
    const float* A2   = (const float*)d_in[8];
    const float* B2   = (const float*)d_in[9];
    const float* gw   = (const float*)d_in[10];
    const float* gb   = (const float*)d_in[11];
    const float* cw   = (const float*)d_in[12];
    const float* cb   = (const float*)d_in[13];
    const float* fc1w = (const float*)d_in[14];
    const float* fc1b = (const float*)d_in[15];
    const float* fc2w = (const float*)d_in[16];
    const float* fc2b = (const float*)d_in[17];
    float* out = (float*)d_out;

    float* ws = (float*)d_ws;
    size_t off = 0;
    auto alloc = [&](size_t n) {
        float* p = ws + off;
        off += (n + 63) & ~(size_t)63;
        return p;
    };
    float* tw      = alloc(2 * HP);
    float* Ct      = alloc(68 * 68);
    float* Sn      = alloc(64 * 68);
    float* Tb      = alloc(64 * 68 * 2);
    float* TE      = alloc(28 * 132);
    float* h_a     = alloc((size_t)BB * HP * SLAB + 8 * HPP);
    float* h_b     = alloc((size_t)BB * HP * SLAB + 8 * HPP);
    float* f1t     = alloc((size_t)BB * CC * HP * KF * 2);
    float* top     = alloc((size_t)BB * CC * MM * MM * 2);
    float* bot     = alloc((size_t)BB * CC * MM * MM * 2);
    float* otop    = alloc((size_t)BB * CC * MM * MM * 2);
    float* obot    = alloc((size_t)BB * CC * MM * MM * 2);
    float* sumabs3 = alloc(BB * CC * 3);
    float* d1      = alloc((size_t)BB * CC * CC * 2);
    float* d2      = alloc((size_t)BB * CC * CC * 2);

    hipLaunchKernelGGL(k_tables, dim3(40), dim3(256), 0, stream, tw, Ct, Sn, Tb, TE);
    hipLaunchKernelGGL(k_fc0, dim3(BB * HP), dim3(256), 0, stream, x, grd, fc0w, fc0b, h_a);

    float* hc = h_a;
    float* hn = h_b;
    for (int l = 0; l < 4; ++l) {
        hipLaunchKernelGGL(k_dftA, dim3(BB * CC * 2), dim3(256), 0, stream, hc, Ct, Sn, f1t);
        hipLaunchKernelGGL(k_dftB, dim3(BB * CC * 3), dim3(DBT), 0, stream,
                           f1t, Tb, sumabs3, top, bot);
        hipLaunchKernelGGL(k_moe, dim3(BB * CC), dim3(128), 0, stream, sumabs3,
                           gw + (size_t)l * CC * EE, gb + (size_t)l * EE,
                           A1 + (size_t)l * EE * CC * RR * 2, B1 + (size_t)l * EE * RR * CC * 2,
                           A2 + (size_t)l * EE * CC * RR * 2, B2 + (size_t)l * EE * RR * CC * 2,
                           d1, d2);
        hipLaunchKernelGGL(k_spec, dim3(256, 2), dim3(192), 0, stream,
                           top, W1 + (size_t)l * CC * CC * MM * MM * 2, d1, otop,
                           bot, W2 + (size_t)l * CC * CC * MM * MM * 2, d2, obot);
        hipLaunchKernelGGL(k_icol, dim3(BB * CC), dim3(256), 0, stream, otop, obot, tw, f1t);
        hipLaunchKernelGGL(k_conv, dim3(BB * HP), dim3(CVT3), 0, stream,
                           hc, f1t, cw + (size_t)l * CC * CC, cb + (size_t)l * CC, TE,
                           hn, (l < 3) ? 1 : 0);
        float* tswap = hc; hc = hn; hn = tswap;
    }
    hipLaunchKernelGGL(k_head, dim3(BB * HS), dim3(HDT), 0, stream,
                       hc, fc1w, fc1b, fc2w, fc2b, out);
}